// Round 6
// baseline (313.354 us; speedup 1.0000x reference)
//
#include <hip/hip_runtime.h>
#include <hip/hip_bf16.h>
#include <math.h>

constexpr int B = 64, S = 1024, H = 1024;

typedef __attribute__((ext_vector_type(8))) short bf16x8;
typedef __attribute__((ext_vector_type(4))) float f32x4;

// f32 -> bf16 (round-to-nearest-even), branchless
__device__ __forceinline__ short f2bf(float f) {
    unsigned u = __builtin_bit_cast(unsigned, f);
    unsigned r = (u + 0x7fffu + ((u >> 16) & 1u)) >> 16;
    return (short)r;
}

__device__ __forceinline__ float tanh_fast(float x) {
    return 1.0f - 2.0f / (__expf(2.0f * x) + 1.0f);
}

__device__ __forceinline__ void gload_lds16(const void* g, void* l) {
    __builtin_amdgcn_global_load_lds(
        (const __attribute__((address_space(1))) unsigned int*)g,
        (__attribute__((address_space(3))) unsigned int*)(uintptr_t)l,
        16, 0, 0);
}

// ---------------------------------------------------------------------------
// Kernel 1: hb[b][o] = attn_b[o] + sum_h hidden[b,h] * attn_W[o,h]   (f32)
// ---------------------------------------------------------------------------
__global__ __launch_bounds__(256) void k_hproj(const float* __restrict__ hidden,
                                               const float* __restrict__ attn_W,
                                               const float* __restrict__ attn_b,
                                               float* __restrict__ hb) {
    int wid  = blockIdx.x * 4 + (threadIdx.x >> 6);
    int lane = threadIdx.x & 63;
    int b = wid >> 10;
    int o = wid & 1023;
    const float* hrow = hidden + (size_t)b * H;
    const float* wrow = attn_W + (size_t)o * (2 * H);
    float acc = 0.f;
#pragma unroll
    for (int k = 0; k < 4; ++k) {
        int idx = lane * 4 + k * 256;
        float4 hv = *(const float4*)(hrow + idx);
        float4 wv = *(const float4*)(wrow + idx);
        acc += hv.x * wv.x + hv.y * wv.y + hv.z * wv.z + hv.w * wv.w;
    }
#pragma unroll
    for (int off = 32; off > 0; off >>= 1) acc += __shfl_down(acc, off, 64);
    if (lane == 0) hb[(size_t)b * H + o] = acc + attn_b[o];
}

// ---------------------------------------------------------------------------
// Kernel 2: convert We = attn_W[:, H:] -> bf16, pre-swizzled.
// Granule (8 bf16 = 16B) id: (((nbq*16 + ks)*256 + n)*8 + gphys),
// gphys = glog ^ (n & 7); holds We[nbq*256+n][ks*64 + glog*8 .. +7].
// ---------------------------------------------------------------------------
__global__ __launch_bounds__(256) void k_convW(const float* __restrict__ attn_W,
                                               short* __restrict__ WeB) {
    int gid = blockIdx.x * 256 + threadIdx.x;     // 131072 granules
    int gphys = gid & 7;
    int n     = (gid >> 3) & 255;
    int ks    = (gid >> 11) & 15;
    int nbq   = gid >> 15;
    int glog  = gphys ^ (n & 7);
    int o  = nbq * 256 + n;
    int k0 = ks * 64 + glog * 8;
    const float* src = attn_W + (size_t)o * (2 * H) + H + k0;
    float4 v0 = *(const float4*)src;
    float4 v1 = *(const float4*)(src + 4);
    bf16x8 pk;
    pk[0] = f2bf(v0.x); pk[1] = f2bf(v0.y); pk[2] = f2bf(v0.z); pk[3] = f2bf(v0.w);
    pk[4] = f2bf(v1.x); pk[5] = f2bf(v1.y); pk[6] = f2bf(v1.z); pk[7] = f2bf(v1.w);
    *(bf16x8*)(WeB + (size_t)gid * 8) = pk;
}

// ---------------------------------------------------------------------------
// Kernel 3: MFMA energy GEMM + tanh + v_W-dot epilogue.
// Grid (nbq=4 fastest, Mtile=1024). 256 thr = 4 waves, wave tile 64x64.
// LDS exactly 80 KB -> 2 blocks/CU (two independent barrier groups overlap
// each other's vmcnt-drain stalls). BK=64, dbuf A and B, conflict-free XOR
// swizzle, B via global_load_lds from pre-swizzled panel, A reg-staged (T14).
// ---------------------------------------------------------------------------
__global__ __launch_bounds__(256, 2) void k_mfma(const float* __restrict__ enc,
                                                 const short* __restrict__ WeB,
                                                 const float* __restrict__ v_W,
                                                 const float* __restrict__ hb,
                                                 float* __restrict__ pscore) {
    __shared__ short Abuf[2][64 * 64];    // 16 KB
    __shared__ short Bbuf[2][256 * 64];   // 64 KB   (total 80 KB)

    const int tid  = threadIdx.x;
    const int lane = tid & 63;
    const int wv   = tid >> 6;        // 0..3
    const int t16  = lane & 15;
    const int q    = lane >> 4;
    const int nbq   = blockIdx.x;     // fastest -> 4 partners co-resident
    const int Mtile = blockIdx.y;
    const int b  = Mtile >> 4;
    const int s0 = (Mtile & 15) * 64;

    // A staging roles: 4 threads per row, each 16 consecutive floats (2 granules)
    const int am = tid >> 2;          // row 0..63
    const int g0 = (tid & 3) * 2;     // first granule 0,2,4,6
    const float* abase = enc + ((size_t)(s0 + am) * B + b) * H + g0 * 8;
    const int s7 = am & 7;
    const int ap0 = (g0 ^ s7) * 8;          // physical bf16 offset of granule g0
    const int ap1 = ((g0 + 1) ^ s7) * 8;

    const char* bpanel0 = (const char*)WeB + (size_t)nbq * 16 * 32768; // 32KB/ks

    f32x4 acc[4][4];
#pragma unroll
    for (int mf = 0; mf < 4; ++mf)
#pragma unroll
        for (int nf = 0; nf < 4; ++nf) acc[mf][nf] = (f32x4){0.f, 0.f, 0.f, 0.f};

    const int nwv = wv * 64;
    const int swz = t16 & 7;

    // ---- prologue: stage k-step 0 into buf 0
    {
#pragma unroll
        for (int r = 0; r < 8; ++r)
            gload_lds16(bpanel0 + (r * 256 + tid) * 16,
                        (char*)&Bbuf[0][0] + (r * 256 + tid) * 16);
        float4 v0 = *(const float4*)(abase);
        float4 v1 = *(const float4*)(abase + 4);
        float4 v2 = *(const float4*)(abase + 8);
        float4 v3 = *(const float4*)(abase + 12);
        bf16x8 p0, p1;
        p0[0] = f2bf(v0.x); p0[1] = f2bf(v0.y); p0[2] = f2bf(v0.z); p0[3] = f2bf(v0.w);
        p0[4] = f2bf(v1.x); p0[5] = f2bf(v1.y); p0[6] = f2bf(v1.z); p0[7] = f2bf(v1.w);
        p1[0] = f2bf(v2.x); p1[1] = f2bf(v2.y); p1[2] = f2bf(v2.z); p1[3] = f2bf(v2.w);
        p1[4] = f2bf(v3.x); p1[5] = f2bf(v3.y); p1[6] = f2bf(v3.z); p1[7] = f2bf(v3.w);
        *(bf16x8*)&Abuf[0][am * 64 + ap0] = p0;
        *(bf16x8*)&Abuf[0][am * 64 + ap1] = p1;
    }
    __syncthreads();

    // ---- main K loop: 16 steps of BK=64
    for (int ks = 0; ks < 16; ++ks) {
        const int cur = ks & 1;
        const int nxt = cur ^ 1;
        float4 v0, v1, v2, v3;
        const bool pf = (ks < 15);
        if (pf) {
            // T14 issue-early: A global loads to regs
            const float* asrc = abase + (ks + 1) * 64;
            v0 = *(const float4*)(asrc);
            v1 = *(const float4*)(asrc + 4);
            v2 = *(const float4*)(asrc + 8);
            v3 = *(const float4*)(asrc + 12);
            // B async direct-to-LDS
            const char* bsrc = bpanel0 + (size_t)(ks + 1) * 32768;
            if (nxt) {
#pragma unroll
                for (int r = 0; r < 8; ++r)
                    gload_lds16(bsrc + (r * 256 + tid) * 16,
                                (char*)&Bbuf[1][0] + (r * 256 + tid) * 16);
            } else {
#pragma unroll
                for (int r = 0; r < 8; ++r)
                    gload_lds16(bsrc + (r * 256 + tid) * 16,
                                (char*)&Bbuf[0][0] + (r * 256 + tid) * 16);
            }
        }

        const short* Ab = &Abuf[cur][0];
        const short* Bb = &Bbuf[cur][0];
#pragma unroll
        for (int kh = 0; kh < 2; ++kh) {
            const int gq = kh * 4 + q;
            const int gp = (gq ^ swz) * 8;
            bf16x8 af[4], bfr[4];
#pragma unroll
            for (int mf = 0; mf < 4; ++mf)
                af[mf] = *(const bf16x8*)(Ab + (mf * 16 + t16) * 64 + gp);
#pragma unroll
            for (int nf = 0; nf < 4; ++nf)
                bfr[nf] = *(const bf16x8*)(Bb + (nwv + nf * 16 + t16) * 64 + gp);
#pragma unroll
            for (int mf = 0; mf < 4; ++mf)
#pragma unroll
                for (int nf = 0; nf < 4; ++nf)
                    acc[mf][nf] = __builtin_amdgcn_mfma_f32_16x16x32_bf16(
                        af[mf], bfr[nf], acc[mf][nf], 0, 0, 0);
        }

        if (pf) {
            // T14 write-late
            bf16x8 p0, p1;
            p0[0] = f2bf(v0.x); p0[1] = f2bf(v0.y); p0[2] = f2bf(v0.z); p0[3] = f2bf(v0.w);
            p0[4] = f2bf(v1.x); p0[5] = f2bf(v1.y); p0[6] = f2bf(v1.z); p0[7] = f2bf(v1.w);
            p1[0] = f2bf(v2.x); p1[1] = f2bf(v2.y); p1[2] = f2bf(v2.z); p1[3] = f2bf(v2.w);
            p1[4] = f2bf(v3.x); p1[5] = f2bf(v3.y); p1[6] = f2bf(v3.z); p1[7] = f2bf(v3.w);
            *(bf16x8*)&Abuf[nxt][am * 64 + ap0] = p0;
            *(bf16x8*)&Abuf[nxt][am * 64 + ap1] = p1;
        }
        __syncthreads();
    }

    // ---- epilogue: tanh + v_W dot over this block's 256 o-cols
    float psum[4][4];
#pragma unroll
    for (int mf = 0; mf < 4; ++mf)
#pragma unroll
        for (int r = 0; r < 4; ++r) psum[mf][r] = 0.f;

#pragma unroll
    for (int nf = 0; nf < 4; ++nf) {
        const int o = nbq * 256 + nwv + nf * 16 + t16;
        const float hbv = hb[(size_t)b * H + o];
        const float vw  = v_W[o];
#pragma unroll
        for (int mf = 0; mf < 4; ++mf)
#pragma unroll
            for (int r = 0; r < 4; ++r)
                psum[mf][r] += vw * tanh_fast(acc[mf][nf][r] + hbv);
    }
#pragma unroll
    for (int mf = 0; mf < 4; ++mf)
#pragma unroll
        for (int r = 0; r < 4; ++r) {
#pragma unroll
            for (int off = 1; off < 16; off <<= 1)
                psum[mf][r] += __shfl_xor(psum[mf][r], off, 64);
        }

    // reuse dead Abuf as reduction scratch (red[64][4])
    float* red = (float*)&Abuf[0][0];
    if (t16 == 0) {
#pragma unroll
        for (int mf = 0; mf < 4; ++mf)
#pragma unroll
            for (int r = 0; r < 4; ++r)
                red[(mf * 16 + q * 4 + r) * 4 + wv] = psum[mf][r];
    }
    __syncthreads();
    if (tid < 64) {
        float s = red[tid * 4 + 0] + red[tid * 4 + 1] + red[tid * 4 + 2] + red[tid * 4 + 3];
        pscore[(size_t)nbq * (B * S) + (size_t)Mtile * 64 + tid] = s;
    }
}

// ---------------------------------------------------------------------------
// Kernel 4: combine 4 partials + mask + softmax over S. One block per b.
// ---------------------------------------------------------------------------
__global__ __launch_bounds__(256) void k_softmax(const float* __restrict__ pscore,
                                                 const int* __restrict__ mask,
                                                 float* __restrict__ out) {
    const int b = blockIdx.x;
    const int tid = threadIdx.x;
    __shared__ float sm[64];
    float v[4];
    float mx = -INFINITY;
#pragma unroll
    for (int k = 0; k < 4; ++k) {
        const int s = tid + k * 256;
        const size_t idx = (size_t)b * S + s;
        float sc = pscore[idx] + pscore[(size_t)(B * S) + idx]
                 + pscore[2 * (size_t)(B * S) + idx] + pscore[3 * (size_t)(B * S) + idx];
        sc = (mask[idx] == 0) ? -1e10f : sc;
        v[k] = sc;
        mx = fmaxf(mx, sc);
    }
#pragma unroll
    for (int off = 32; off > 0; off >>= 1) mx = fmaxf(mx, __shfl_down(mx, off, 64));
    if ((tid & 63) == 0) sm[tid >> 6] = mx;
    __syncthreads();
    if (tid == 0) {
        float m = sm[0];
        for (int k = 1; k < 4; ++k) m = fmaxf(m, sm[k]);
        sm[4] = m;
    }
    __syncthreads();
    mx = sm[4];
    float sum = 0.f;
#pragma unroll
    for (int k = 0; k < 4; ++k) { v[k] = __expf(v[k] - mx); sum += v[k]; }
#pragma unroll
    for (int off = 32; off > 0; off >>= 1) sum += __shfl_down(sum, off, 64);
    if ((tid & 63) == 0) sm[8 + (tid >> 6)] = sum;
    __syncthreads();
    if (tid == 0) sm[12] = sm[8] + sm[9] + sm[10] + sm[11];
    __syncthreads();
    const float inv = 1.f / sm[12];
#pragma unroll
    for (int k = 0; k < 4; ++k) out[(size_t)b * S + tid + k * 256] = v[k] * inv;
}

// ---------------------------------------------------------------------------
extern "C" void kernel_launch(void* const* d_in, const int* in_sizes, int n_in,
                              void* d_out, int out_size, void* d_ws, size_t ws_size,
                              hipStream_t stream) {
    const float* hidden = (const float*)d_in[0];   // (B,H)
    const float* enc    = (const float*)d_in[1];   // (S,B,H)
    const int*   mask   = (const int*)d_in[2];     // (B,S)
    const float* attn_W = (const float*)d_in[3];   // (H,2H)
    const float* attn_b = (const float*)d_in[4];   // (H,)
    const float* v_W    = (const float*)d_in[5];   // (H,)
    float* out = (float*)d_out;                    // (B,S)

    float* hb     = (float*)d_ws;                          // 64K f32   (256 KB)
    short* WeB    = (short*)(hb + (size_t)B * H);          // 1M bf16   (2 MB)
    float* pscore = (float*)(WeB + (size_t)H * H);         // 256K f32  (1 MB)

    k_hproj<<<dim3((B * H) / 4), 256, 0, stream>>>(hidden, attn_W, attn_b, hb);
    k_convW<<<dim3(512), 256, 0, stream>>>(attn_W, WeB);
    k_mfma<<<dim3(4, 1024), 256, 0, stream>>>(enc, WeB, v_W, hb, pscore);
    k_softmax<<<dim3(B), 256, 0, stream>>>(pscore, mask, out);
}